// Round 5
// baseline (468.768 us; speedup 1.0000x reference)
//
#include <hip/hip_runtime.h>
#include <math.h>

#define BB 4
#define SS 1024
#define DD 768
#define HH 12
#define DHH 64

typedef __attribute__((ext_vector_type(8))) short bf16x8;   // 8 bf16 = 4 VGPR
typedef __attribute__((ext_vector_type(4))) float f32x4;    // MFMA acc

__device__ __forceinline__ unsigned int f2bf(float f) {
    unsigned int u = __float_as_uint(f);
    return (u + 0x7FFFu + ((u >> 16) & 1u)) >> 16;   // RNE
}
__device__ __forceinline__ float bf2f(unsigned int h) {
    return __uint_as_float(h << 16);
}

// async global->LDS, 16B per lane. dest must be wave-uniform base (+lane*16 by HW).
__device__ __forceinline__ void glds16(const void* g, void* l) {
    __builtin_amdgcn_global_load_lds(
        (const __attribute__((address_space(1))) void*)g,
        (__attribute__((address_space(3))) void*)l, 16, 0, 0);
}

// ======================================================================
// prep: fp32 -> bf16 convert of hidden
// ======================================================================
__global__ __launch_bounds__(256)
void cvt_hidden_kernel(const float* __restrict__ src, unsigned short* __restrict__ dst)
{
    const int idx = (blockIdx.x * 256 + threadIdx.x) * 8;
    float4 a = *(const float4*)&src[idx];
    float4 b = *(const float4*)&src[idx + 4];
    uint4 p;
    p.x = f2bf(a.x) | (f2bf(a.y) << 16);
    p.y = f2bf(a.z) | (f2bf(a.w) << 16);
    p.z = f2bf(b.x) | (f2bf(b.y) << 16);
    p.w = f2bf(b.z) | (f2bf(b.w) << 16);
    *(uint4*)&dst[idx] = p;
}

// ======================================================================
// prep: W[k][n] fp32 -> Wt[w][n][k] bf16 (transposed, n-major)
// ======================================================================
__global__ __launch_bounds__(256)
void transpose_w_kernel(const float* __restrict__ Wq, const float* __restrict__ Wk,
                        const float* __restrict__ Wv, const float* __restrict__ Wo,
                        unsigned short* __restrict__ Wt)
{
    __shared__ float tile[32][33];
    const int t = threadIdx.x;
    const int kt = blockIdx.x, nt = blockIdx.y, w = blockIdx.z;
    const float* src = (w == 0) ? Wq : (w == 1) ? Wk : (w == 2) ? Wv : Wo;
    const int r = t >> 3, c4 = (t & 7) * 4;
    float4 v = *(const float4*)&src[(kt * 32 + r) * DD + nt * 32 + c4];
    tile[r][c4 + 0] = v.x; tile[r][c4 + 1] = v.y;
    tile[r][c4 + 2] = v.z; tile[r][c4 + 3] = v.w;
    __syncthreads();
    uint2 p;
    p.x = f2bf(tile[c4 + 0][r]) | (f2bf(tile[c4 + 1][r]) << 16);
    p.y = f2bf(tile[c4 + 2][r]) | (f2bf(tile[c4 + 3][r]) << 16);
    *(uint2*)&Wt[((size_t)w * DD + nt * 32 + r) * DD + kt * 32 + c4] = p;
}

// ======================================================================
// shared MFMA GEMM core: 64x64 tile, K=768 in 12 chunks of 64.
// LDS tiles 64x128B, XOR swizzle (kb ^= row&7) on glds SOURCE and reads.
// 4 waves 2x2; wave tile 32x32 (2x2 frags of 16x16).
// ======================================================================
__device__ __forceinline__ void gemm_core64(
    const char* __restrict__ Ag, const char* __restrict__ Bg,
    char* As, char* Bs, int tid, f32x4 (&acc)[2][2])
{
    const int lane = tid & 63;
    const int wr = (tid >> 7) & 1;
    const int wc = (tid >> 6) & 1;
    const int ldst = (tid & 192) << 4;   // wave * 1024 bytes

    for (int c = 0; c < 12; ++c) {
        const int kbyte = c * 128;
        #pragma unroll
        for (int i = 0; i < 2; ++i) {
            const int s = i * 256 + tid;
            const int row = s >> 3, kb = s & 7;
            const size_t off = (size_t)row * 1536 + kbyte + ((kb ^ (row & 7)) << 4);
            glds16(Ag + off, As + i * 4096 + ldst);
            glds16(Bg + off, Bs + i * 4096 + ldst);
        }
        __syncthreads();
        #pragma unroll
        for (int ks = 0; ks < 2; ++ks) {
            const int kb = ks * 4 + (lane >> 4);
            bf16x8 a[2], b[2];
            #pragma unroll
            for (int mi = 0; mi < 2; ++mi) {
                const int row = wr * 32 + mi * 16 + (lane & 15);
                a[mi] = *(const bf16x8*)(As + row * 128 + ((kb ^ (row & 7)) << 4));
            }
            #pragma unroll
            for (int ni = 0; ni < 2; ++ni) {
                const int row = wc * 32 + ni * 16 + (lane & 15);
                b[ni] = *(const bf16x8*)(Bs + row * 128 + ((kb ^ (row & 7)) << 4));
            }
            #pragma unroll
            for (int mi = 0; mi < 2; ++mi)
                #pragma unroll
                for (int ni = 0; ni < 2; ++ni)
                    acc[mi][ni] = __builtin_amdgcn_mfma_f32_16x16x32_bf16(
                        a[mi], b[ni], acc[mi][ni], 0, 0, 0);
        }
        __syncthreads();
    }
}

// ======================================================================
// QKV projection. Q,K -> bf16 [B,H,S,DH]; V -> bf16 [B,H,DH,S].
// Epilogue: LDS repack (swizzled) -> coalesced dwordx4 stores.
// ======================================================================
__global__ __launch_bounds__(256)
void qkv_gemm_kernel(const unsigned short* __restrict__ hbf, const unsigned short* __restrict__ Wt,
                     const float* __restrict__ bq, const float* __restrict__ bk,
                     const float* __restrict__ bv,
                     unsigned short* __restrict__ Qb, unsigned short* __restrict__ Kb,
                     unsigned short* __restrict__ Vtb)
{
    __shared__ __align__(16) char As[8192];
    __shared__ __align__(16) char Bs[8192];
    const int tid = threadIdx.x;
    const int m0 = blockIdx.x * 64;
    const int w = blockIdx.y / 12;
    const int n0w = (blockIdx.y % 12) * 64;

    f32x4 acc[2][2];
    const f32x4 z4 = {0.f, 0.f, 0.f, 0.f};
    acc[0][0] = z4; acc[0][1] = z4; acc[1][0] = z4; acc[1][1] = z4;

    const char* Ag = (const char*)hbf + (size_t)m0 * 1536;
    const char* Bg = (const char*)Wt + ((size_t)w * DD + n0w) * 1536;
    gemm_core64(Ag, Bg, As, Bs, tid, acc);

    const int lane = tid & 63;
    const int wr = (tid >> 7) & 1, wc = (tid >> 6) & 1;
    const int b = m0 >> 10, s0 = m0 & 1023;
    const int h = n0w >> 6;
    const float* bias = (w == 0) ? bq : (w == 1) ? bk : bv;

    if (w == 2) {
        // tile [64 d][64 s] bf16 in As
        #pragma unroll
        for (int mi = 0; mi < 2; ++mi)
            #pragma unroll
            for (int ni = 0; ni < 2; ++ni) {
                const int drow = wc * 32 + ni * 16 + (lane & 15);
                const float bb = bias[n0w + drow];
                #pragma unroll
                for (int r = 0; r < 4; ++r) {
                    const int scol = wr * 32 + mi * 16 + (lane >> 4) * 4 + r;
                    const int byte = (drow * 128 + scol * 2) ^ ((drow & 7) << 4);
                    *(unsigned short*)(As + byte) = (unsigned short)f2bf(acc[mi][ni][r] + bb);
                }
            }
        __syncthreads();
        const int drow = tid >> 2, c32 = (tid & 3) * 32;
        const int sw = (drow & 7) << 4;
        uint4 lo = *(uint4*)(As + ((drow * 128 + c32) ^ sw));
        uint4 hi = *(uint4*)(As + ((drow * 128 + c32 + 16) ^ sw));
        char* dst = (char*)Vtb + ((((size_t)(b * HH + h) * DHH) + drow) * SS + s0) * 2 + c32;
        *(uint4*)dst = lo; *(uint4*)(dst + 16) = hi;
    } else {
        // tile [64 s][64 d] bf16 in As
        #pragma unroll
        for (int mi = 0; mi < 2; ++mi)
            #pragma unroll
            for (int ni = 0; ni < 2; ++ni) {
                const int ncol = wc * 32 + ni * 16 + (lane & 15);
                const float bb = bias[n0w + ncol];
                #pragma unroll
                for (int r = 0; r < 4; ++r) {
                    const int srow = wr * 32 + mi * 16 + (lane >> 4) * 4 + r;
                    const int byte = (srow * 128 + ncol * 2) ^ ((srow & 7) << 4);
                    *(unsigned short*)(As + byte) = (unsigned short)f2bf(acc[mi][ni][r] + bb);
                }
            }
        __syncthreads();
        const int srow = tid >> 2, c32 = (tid & 3) * 32;
        const int sw = (srow & 7) << 4;
        uint4 lo = *(uint4*)(As + ((srow * 128 + c32) ^ sw));
        uint4 hi = *(uint4*)(As + ((srow * 128 + c32 + 16) ^ sw));
        unsigned short* base = (w == 0) ? Qb : Kb;
        char* dst = (char*)base + (((size_t)(b * HH + h) * SS + s0 + srow) * DHH) * 2 + c32;
        *(uint4*)dst = lo; *(uint4*)(dst + 16) = hi;
    }
}

// ======================================================================
// qk_exp: block = (b,h, 64 q rows); E1 = exp(QK^T/8 + mask) bf16; Z1 row sums.
// E1 staged in 8KB LDS sub-tiles (64q x 64k) -> coalesced dwordx4 stores.
// ======================================================================
__global__ __launch_bounds__(256)
void qk_exp_kernel(const unsigned short* __restrict__ Qb, const unsigned short* __restrict__ Kb,
                   const float* __restrict__ mask,
                   unsigned short* __restrict__ E1, float* __restrict__ Z1)
{
    __shared__ __align__(16) char Ks[32768];
    __shared__ __align__(16) char Es[8192];
    const int tid = threadIdx.x;
    const int lane = tid & 63;
    const int wv = tid >> 6;
    const int bh = blockIdx.x >> 4;
    const int q0 = (blockIdx.x & 15) * 64;
    const int b = bh / HH;
    const int qw = q0 + wv * 16;
    const int ldst = (tid & 192) << 4;

    const char* Qrow = (const char*)Qb + ((size_t)bh * SS + qw + (lane & 15)) * 128;
    bf16x8 aq0 = *(const bf16x8*)(Qrow + (lane >> 4) * 16);
    bf16x8 aq1 = *(const bf16x8*)(Qrow + 64 + (lane >> 4) * 16);

    float zr[4] = {0.f, 0.f, 0.f, 0.f};
    const char* Kbase = (const char*)Kb + (size_t)bh * SS * 128;

    for (int c = 0; c < 4; ++c) {
        #pragma unroll
        for (int i = 0; i < 8; ++i) {
            const int s = i * 256 + tid;
            const int row = s >> 3, kb = s & 7;
            glds16(Kbase + (size_t)(c * 256 + row) * 128 + ((kb ^ (row & 7)) << 4),
                   Ks + i * 4096 + ldst);
        }
        __syncthreads();
        for (int kg = 0; kg < 4; ++kg) {
            #pragma unroll
            for (int nfi = 0; nfi < 4; ++nfi) {
                const int nf = kg * 4 + nfi;
                const int krow = nf * 16 + (lane & 15);
                const int kx = krow & 7;
                bf16x8 b0 = *(const bf16x8*)(Ks + krow * 128 + (((lane >> 4) ^ kx) << 4));
                bf16x8 b1 = *(const bf16x8*)(Ks + krow * 128 + (((4 + (lane >> 4)) ^ kx) << 4));
                f32x4 accf = {0.f, 0.f, 0.f, 0.f};
                accf = __builtin_amdgcn_mfma_f32_16x16x32_bf16(aq0, b0, accf, 0, 0, 0);
                accf = __builtin_amdgcn_mfma_f32_16x16x32_bf16(aq1, b1, accf, 0, 0, 0);
                const int kcol = c * 256 + krow;
                const float mk = mask[b * SS + kcol];
                const int kl = nfi * 16 + (lane & 15);
                #pragma unroll
                for (int r = 0; r < 4; ++r) {
                    const int ql = wv * 16 + (lane >> 4) * 4 + r;
                    const float e = __expf(accf[r] * 0.125f + mk);
                    zr[r] += e;
                    const int byte = (ql * 128 + kl * 2) ^ ((ql & 7) << 4);
                    *(unsigned short*)(Es + byte) = (unsigned short)f2bf(e);
                }
            }
            __syncthreads();
            {
                const int ql = tid >> 2, c32 = (tid & 3) * 32;
                const int sw = (ql & 7) << 4;
                uint4 lo = *(uint4*)(Es + ((ql * 128 + c32) ^ sw));
                uint4 hi = *(uint4*)(Es + ((ql * 128 + c32 + 16) ^ sw));
                char* dst = (char*)E1 + ((size_t)bh * SS + q0 + ql) * 2048
                          + (c * 256 + kg * 64) * 2 + c32;
                *(uint4*)dst = lo; *(uint4*)(dst + 16) = hi;
            }
            __syncthreads();
        }
    }

    #pragma unroll
    for (int r = 0; r < 4; ++r) {
        float z = zr[r];
        z += __shfl_xor(z, 1); z += __shfl_xor(z, 2);
        z += __shfl_xor(z, 4); z += __shfl_xor(z, 8);
        if ((lane & 15) == 0)
            Z1[(size_t)bh * SS + qw + (lane >> 4) * 4 + r] = z;
    }
}

// ======================================================================
// e2: streaming. block = (b,q). E2 = exp(0.5*conv(prev)+0.5*E1/Z1) written
// IN PLACE over E1 (bf16); Z2 row sums per head.
// ======================================================================
__global__ __launch_bounds__(256)
void e2_kernel(unsigned short* __restrict__ E1, const float* __restrict__ Z1,
               const float* __restrict__ prev, const float* __restrict__ cw,
               const float* __restrict__ cb, float* __restrict__ Z2)
{
    __shared__ float cws[144], cbs[12], izs[12], zred[4][12];
    const int t = threadIdx.x;
    const int b = blockIdx.x >> 10;
    const int q = blockIdx.x & 1023;

    if (t < 144) cws[t] = cw[t];
    if (t < 12) {
        cbs[t] = cb[t];
        izs[t] = 1.0f / Z1[((size_t)(b * HH + t)) * SS + q];
    }
    __syncthreads();

    float z2[12];
    #pragma unroll
    for (int h = 0; h < 12; ++h) z2[h] = 0.f;

    #pragma unroll
    for (int c = 0; c < 2; ++c) {
        const int k = c * 512 + t * 2;
        float2 pv[12];
        #pragma unroll
        for (int i = 0; i < 12; ++i)
            pv[i] = *(const float2*)&prev[(((size_t)(b * HH + i)) * SS + q) * SS + k];
        const size_t e1base = (((size_t)(b * HH)) * SS + q) * SS + k;
        #pragma unroll
        for (int h = 0; h < 12; ++h) {
            float mix0 = cbs[h], mix1 = cbs[h];
            #pragma unroll
            for (int i = 0; i < 12; ++i) {
                mix0 = fmaf(cws[h * 12 + i], pv[i].x, mix0);
                mix1 = fmaf(cws[h * 12 + i], pv[i].y, mix1);
            }
            unsigned int u = *(unsigned int*)&E1[e1base + (size_t)h * SS * SS];
            const float p10 = bf2f(u & 0xFFFFu) * izs[h];
            const float p11 = bf2f(u >> 16) * izs[h];
            const float e0 = __expf(0.5f * (mix0 + p10));
            const float e1 = __expf(0.5f * (mix1 + p11));
            z2[h] += e0 + e1;
            *(unsigned int*)&E1[e1base + (size_t)h * SS * SS] = f2bf(e0) | (f2bf(e1) << 16);
        }
    }

    #pragma unroll
    for (int h = 0; h < 12; ++h) {
        float z = z2[h];
        for (int off = 32; off; off >>= 1) z += __shfl_xor(z, off);
        z2[h] = z;
    }
    if ((t & 63) == 0) {
        const int wv = t >> 6;
        #pragma unroll
        for (int h = 0; h < 12; ++h) zred[wv][h] = z2[h];
    }
    __syncthreads();
    if (t < 12)
        Z2[((size_t)(b * HH + t)) * SS + q] =
            zred[0][t] + zred[1][t] + zred[2][t] + zred[3][t];
}

// ======================================================================
// PV: block = (b,h, 64 q); ctx[q][h*64+d] = (E2 @ V) / Z2, bf16 out.
// Epilogue repack via Es -> coalesced stores.
// ======================================================================
__global__ __launch_bounds__(256)
void pv_kernel(const unsigned short* __restrict__ E2, const float* __restrict__ Z2,
               const unsigned short* __restrict__ Vtb, unsigned short* __restrict__ ctx)
{
    __shared__ __align__(16) char Es[8192];
    __shared__ __align__(16) char Vs[8192];
    const int tid = threadIdx.x;
    const int lane = tid & 63;
    const int wv = tid >> 6;
    const int bh = blockIdx.x >> 4;
    const int q0 = (blockIdx.x & 15) * 64;
    const int b = bh / HH, h = bh % HH;
    const int ldst = (tid & 192) << 4;

    f32x4 acc[4];
    const f32x4 z4 = {0.f, 0.f, 0.f, 0.f};
    acc[0] = z4; acc[1] = z4; acc[2] = z4; acc[3] = z4;

    const char* Ebase = (const char*)E2 + ((size_t)bh * SS + q0) * 2048;
    const char* Vbase = (const char*)Vtb + (size_t)bh * DHH * 2048;

    for (int c = 0; c < 16; ++c) {
        const int kbyte = c * 128;
        #pragma unroll
        for (int i = 0; i < 2; ++i) {
            const int s = i * 256 + tid;
            const int row = s >> 3, kb = s & 7;
            const size_t off = (size_t)row * 2048 + kbyte + ((kb ^ (row & 7)) << 4);
            glds16(Ebase + off, Es + i * 4096 + ldst);
            glds16(Vbase + off, Vs + i * 4096 + ldst);
        }
        __syncthreads();
        #pragma unroll
        for (int ks = 0; ks < 2; ++ks) {
            const int kb = ks * 4 + (lane >> 4);
            const int arow = wv * 16 + (lane & 15);
            bf16x8 a = *(const bf16x8*)(Es + arow * 128 + ((kb ^ (arow & 7)) << 4));
            #pragma unroll
            for (int nf = 0; nf < 4; ++nf) {
                const int vrow = nf * 16 + (lane & 15);
                bf16x8 bb = *(const bf16x8*)(Vs + vrow * 128 + ((kb ^ (vrow & 7)) << 4));
                acc[nf] = __builtin_amdgcn_mfma_f32_16x16x32_bf16(a, bb, acc[nf], 0, 0, 0);
            }
        }
        __syncthreads();
    }

    float iz[4];
    #pragma unroll
    for (int r = 0; r < 4; ++r)
        iz[r] = 1.0f / Z2[(size_t)bh * SS + q0 + wv * 16 + (lane >> 4) * 4 + r];

    // repack ctx tile [64 q][64 d] bf16 into Es (free after loop)
    #pragma unroll
    for (int nf = 0; nf < 4; ++nf) {
        const int d = nf * 16 + (lane & 15);
        #pragma unroll
        for (int r = 0; r < 4; ++r) {
            const int ql = wv * 16 + (lane >> 4) * 4 + r;
            const int byte = (ql * 128 + d * 2) ^ ((ql & 7) << 4);
            *(unsigned short*)(Es + byte) = (unsigned short)f2bf(acc[nf][r] * iz[r]);
        }
    }
    __syncthreads();
    {
        const int ql = tid >> 2, c32 = (tid & 3) * 32;
        const int sw = (ql & 7) << 4;
        uint4 lo = *(uint4*)(Es + ((ql * 128 + c32) ^ sw));
        uint4 hi = *(uint4*)(Es + ((ql * 128 + c32 + 16) ^ sw));
        char* dst = (char*)ctx + ((size_t)(b * SS + q0 + ql) * DD + h * DHH) * 2 + c32;
        *(uint4*)dst = lo; *(uint4*)(dst + 16) = hi;
    }
}

// ======================================================================
// out-projection: ctx bf16 @ Wo_t -> gout fp32 (+bo), repacked epilogue
// ======================================================================
__global__ __launch_bounds__(256)
void o_gemm_kernel(const unsigned short* __restrict__ ctx, const unsigned short* __restrict__ WtO,
                   const float* __restrict__ bo, float* __restrict__ gout)
{
    __shared__ __align__(16) char smem[16384];
    char* As = smem;
    char* Bs = smem + 8192;
    const int tid = threadIdx.x;
    const int m0 = blockIdx.x * 64;
    const int n0 = blockIdx.y * 64;

    f32x4 acc[2][2];
    const f32x4 z4 = {0.f, 0.f, 0.f, 0.f};
    acc[0][0] = z4; acc[0][1] = z4; acc[1][0] = z4; acc[1][1] = z4;

    gemm_core64((const char*)ctx + (size_t)m0 * 1536,
                (const char*)WtO + (size_t)n0 * 1536, As, Bs, tid, acc);

    const int lane = tid & 63;
    const int wr = (tid >> 7) & 1, wc = (tid >> 6) & 1;
    // fp32 tile [64 rows][64 cols] = 16 KB across whole smem
    #pragma unroll
    for (int mi = 0; mi < 2; ++mi)
        #pragma unroll
        for (int ni = 0; ni < 2; ++ni) {
            const int ncol = wc * 32 + ni * 16 + (lane & 15);
            const float bb = bo[n0 + ncol];
            #pragma unroll
            for (int r = 0; r < 4; ++r) {
                const int row = wr * 32 + mi * 16 + (lane >> 4) * 4 + r;
                *(float*)(smem + ((row * 256 + ncol * 4) ^ ((row & 7) << 4))) =
                    acc[mi][ni][r] + bb;
            }
        }
    __syncthreads();
    {
        const int row = tid >> 2, c64 = (tid & 3) * 64;
        const int sw = (row & 7) << 4;
        float4 v[4];
        #pragma unroll
        for (int j = 0; j < 4; ++j)
            v[j] = *(float4*)(smem + ((row * 256 + c64 + j * 16) ^ sw));
        float* dst = gout + (size_t)(m0 + row) * DD + n0 + (tid & 3) * 16;
        #pragma unroll
        for (int j = 0; j < 4; ++j)
            *(float4*)(dst + j * 4) = v[j];
    }
}

// ======================================================================
// Residual + LayerNorm (fp32)
// ======================================================================
__global__ __launch_bounds__(256)
void ln_kernel(const float* __restrict__ go, const float* __restrict__ hid,
               const float* __restrict__ lw, const float* __restrict__ lb,
               float* __restrict__ out)
{
    const int row = blockIdx.x;
    const int tid = threadIdx.x;
    const int lane = tid & 63, wave = tid >> 6;
    __shared__ float wsum[4], wsq[4];

    float x[3];
    float ssum = 0.f, ssq = 0.f;
    #pragma unroll
    for (int j = 0; j < 3; ++j) {
        const int n = tid + j * 256;
        const float v = go[(size_t)row * DD + n] + hid[(size_t)row * DD + n];
        x[j] = v; ssum += v; ssq += v * v;
    }
    for (int off = 32; off; off >>= 1) {
        ssum += __shfl_xor(ssum, off);
        ssq  += __shfl_xor(ssq, off);
    }
    if (lane == 0) { wsum[wave] = ssum; wsq[wave] = ssq; }
    __syncthreads();
    const float tsum = wsum[0] + wsum[1] + wsum[2] + wsum[3];
    const float tsq  = wsq[0] + wsq[1] + wsq[2] + wsq[3];
    const float mean = tsum * (1.0f / 768.0f);
    const float var  = tsq * (1.0f / 768.0f) - mean * mean;
    const float rstd = rsqrtf(var + 1e-12f);
    #pragma unroll
    for (int j = 0; j < 3; ++j) {
        const int n = tid + j * 256;
        out[(size_t)row * DD + n] = lw[n] * ((x[j] - mean) * rstd) + lb[n];
    }
}

extern "C" void kernel_launch(void* const* d_in, const int* in_sizes, int n_in,
                              void* d_out, int out_size, void* d_ws, size_t ws_size,
                              hipStream_t stream)
{
    const float* hidden = (const float*)d_in[0];
    const float* mask   = (const float*)d_in[1];
    const float* prev   = (const float*)d_in[2];
    const float* Wq = (const float*)d_in[3];  const float* bq = (const float*)d_in[4];
    const float* Wk = (const float*)d_in[5];  const float* bk = (const float*)d_in[6];
    const float* Wv = (const float*)d_in[7];  const float* bv = (const float*)d_in[8];
    const float* cw = (const float*)d_in[9];  const float* cb = (const float*)d_in[10];
    const float* Wo = (const float*)d_in[11]; const float* bo = (const float*)d_in[12];
    const float* lw = (const float*)d_in[13]; const float* lb = (const float*)d_in[14];
    float* out = (float*)d_out;

    char* w = (char*)d_ws;
    unsigned short* hbf = (unsigned short*)(w);              //  6 MB
    unsigned short* Wt  = (unsigned short*)(w + 6291456);    //  4.5MB
    unsigned short* Qb  = (unsigned short*)(w + 11010048);   //  6 MB
    unsigned short* Kb  = (unsigned short*)(w + 17301504);   //  6 MB
    unsigned short* Vtb = (unsigned short*)(w + 23592960);   //  6 MB
    unsigned short* E1  = (unsigned short*)(w + 29884416);   // 96 MB (E2 in place)
    float* Z1 = (float*)(w + 130547712);                     // 192 KB
    float* Z2 = (float*)(w + 130744320);                     // 192 KB
    unsigned short* ctx = hbf;                               // alias (hbf dead after QKV)
    float* gout = (float*)(w + 11010048);                    // alias Qb+Kb

    dim3 blk(256);
    cvt_hidden_kernel<<<dim3(1536), blk, 0, stream>>>(hidden, hbf);
    transpose_w_kernel<<<dim3(24, 24, 4), blk, 0, stream>>>(Wq, Wk, Wv, Wo, Wt);
    qkv_gemm_kernel<<<dim3(64, 36), blk, 0, stream>>>(hbf, Wt, bq, bk, bv, Qb, Kb, Vtb);
    qk_exp_kernel<<<dim3(768), blk, 0, stream>>>(Qb, Kb, mask, E1, Z1);
    e2_kernel<<<dim3(4096), blk, 0, stream>>>(E1, Z1, prev, cw, cb, Z2);
    pv_kernel<<<dim3(768), blk, 0, stream>>>(E1, Z2, Vtb, ctx);
    o_gemm_kernel<<<dim3(64, 12), blk, 0, stream>>>(ctx, Wt + (size_t)3 * DD * DD, bo, gout);
    ln_kernel<<<dim3(4096), blk, 0, stream>>>(gout, hidden, lw, lb, out);
}